// Round 5
// baseline (427.443 us; speedup 1.0000x reference)
//
#include <hip/hip_runtime.h>
#include <math.h>

// ---------------------------------------------------------------------------
// SAGPool GNN forward: 3x [GCNConv -> SAGPool(top-k) -> readout] + MLP head.
// B=32 graphs x N=2048 nodes; E=524288; 128 feats; K = 1024/512/256.
// R5 changes vs R4 (385us; k_matmul top @42us, 5M LDS bank conflicts, VALU 40%):
//   - matmul: 256-row tile, 16x8 register tile per thread. Per kk per wave:
//     6 ds_read_b128 (72 cyc) vs 256 FMA cyc -> LDS pipe (shared by 4 SIMDs)
//     balanced against VALU instead of 3x oversubscribed. Staging conflicts
//     now amortized over 32x more FMA.
//   - dispatch count 27 -> 18: scan2+deg0+scale-init folded into scan3
//     (per-block redundant bsum scan); readout2 x3 + gacc folded into k_mlp.
// ---------------------------------------------------------------------------

namespace {

constexpr int B_  = 32;
constexpr int N_  = 2048;
constexpr int NT  = B_ * N_;        // 65536
constexpr int E_  = B_ * 16384;     // 524288
constexpr int NCLS = 10;
constexpr int RPARTS = 32;

// ---- CSR build -------------------------------------------------------------
__global__ void k_count(const int* __restrict__ dst, int* __restrict__ cnt) {
  int e = blockIdx.x * 256 + threadIdx.x;
  if (e < E_) atomicAdd(&cnt[dst[e]], 1);
}

__global__ void k_scan1(const int* __restrict__ cnt, int* __restrict__ off,
                        int* __restrict__ bsum) {
  __shared__ int s[256];
  int t = threadIdx.x;
  int i = blockIdx.x * 256 + t;
  int v = cnt[i];
  s[t] = v;
  __syncthreads();
  for (int d = 1; d < 256; d <<= 1) {
    int add = (t >= d) ? s[t - d] : 0;
    __syncthreads();
    s[t] += add;
    __syncthreads();
  }
  off[i] = s[t] - v;  // exclusive within block
  if (t == 255) bsum[blockIdx.x] = s[255];
}

// scan3': adds bsum prefix (block rescans bsum itself), writes cursor,
// and computes layer-0 deg/dinv/selfw + scale=1 (deg0 fold).
__global__ void k_scan3(int* __restrict__ off, const int* __restrict__ bsum,
                        const int* __restrict__ cnt, int* __restrict__ cursor,
                        float* __restrict__ dinv, float* __restrict__ selfw,
                        float* __restrict__ scale) {
  __shared__ int sb[256];
  int t = threadIdx.x;
  sb[t] = bsum[t];
  __syncthreads();
  for (int d = 1; d < 256; d <<= 1) {
    int add = (t >= d) ? sb[t - d] : 0;
    __syncthreads();
    sb[t] += add;
    __syncthreads();
  }
  int prefix = (blockIdx.x == 0) ? 0 : sb[blockIdx.x - 1];
  int i = blockIdx.x * 256 + t;
  int v = off[i] + prefix;
  off[i] = v;
  cursor[i] = v;
  if (i == NT - 1) off[NT] = E_;
  float d = 1.f + (float)cnt[i];
  float di = 1.f / sqrtf(d);
  dinv[i] = di;
  selfw[i] = di * di;
  scale[i] = 1.f;
}

__global__ void k_fill_srcp(const int* __restrict__ src, const int* __restrict__ dst,
                            int* __restrict__ cursor, int* __restrict__ srcp) {
  int e = blockIdx.x * 256 + threadIdx.x;
  if (e < E_) {
    int p = atomicAdd(&cursor[dst[e]], 1);
    srcp[p] = src[e];
  }
}

// ---- dense matmul: C[rows x 128] = (scale .* A)[rows x 128] @ W ------------
// 256-row tile per 256-thread block; 16 rows x 8 cols per thread.
// A staged transposed [kk][row] (stride 264), W [kk][col] (stride 132).
__global__ __launch_bounds__(256) void k_matmul(const float* __restrict__ A,
                                                const float* __restrict__ scale,
                                                const float* __restrict__ W,
                                                float* __restrict__ C,
                                                const int* __restrict__ kept,
                                                int kshift) {
  __shared__ float Ast[32 * 264];
  __shared__ float Ws[32 * 132];
  __shared__ int rowid[256];
  __shared__ float rsc[256];
  const int tid = threadIdx.x;
  {
    int q = blockIdx.x * 256 + tid;
    int row;
    if (kept) {
      int g = q >> kshift;
      row = kept[g * N_ + (q - (g << kshift))];
    } else {
      row = q;
    }
    rowid[tid] = row;
    rsc[tid] = scale[row];
  }
  __syncthreads();
  const int rowq = tid >> 4;   // 0..15 -> rows 16*rowq..+15
  const int colq = tid & 15;   // 0..15 -> cols 8*colq..+7
  const int rs = tid >> 3;     // staging: row base 0..31
  const int fs = tid & 7;      // staging: k-float4 index 0..7
  float acc[16][8] = {};
  for (int k0 = 0; k0 < 128; k0 += 32) {
    // stage A (256 rows x 32 k), transpose in LDS; scale folded in
#pragma unroll
    for (int i = 0; i < 8; ++i) {
      int r = rs + 32 * i;
      float4 v = *(const float4*)&A[(size_t)rowid[r] * 128 + k0 + 4 * fs];
      float sc = rsc[r];
      Ast[(4 * fs + 0) * 264 + r] = v.x * sc;
      Ast[(4 * fs + 1) * 264 + r] = v.y * sc;
      Ast[(4 * fs + 2) * 264 + r] = v.z * sc;
      Ast[(4 * fs + 3) * 264 + r] = v.w * sc;
    }
    // stage W (32 k x 128 cols)
    {
      int kk = tid >> 3;
#pragma unroll
      for (int i = 0; i < 4; ++i) {
        int cf = fs + 8 * i;
        float4 w = *(const float4*)&W[(size_t)(k0 + kk) * 128 + 4 * cf];
        *(float4*)&Ws[kk * 132 + 4 * cf] = w;
      }
    }
    __syncthreads();
#pragma unroll 2
    for (int kk = 0; kk < 32; ++kk) {
      float a[16], w[8];
      const float* arow = &Ast[kk * 264 + 16 * rowq];
#pragma unroll
      for (int e = 0; e < 4; ++e) {
        float4 v = *(const float4*)&arow[4 * e];
        a[4 * e] = v.x; a[4 * e + 1] = v.y; a[4 * e + 2] = v.z; a[4 * e + 3] = v.w;
      }
      const float* wrow = &Ws[kk * 132 + 8 * colq];
      float4 w0 = *(const float4*)&wrow[0];
      float4 w1 = *(const float4*)&wrow[4];
      w[0] = w0.x; w[1] = w0.y; w[2] = w0.z; w[3] = w0.w;
      w[4] = w1.x; w[5] = w1.y; w[6] = w1.z; w[7] = w1.w;
#pragma unroll
      for (int r = 0; r < 16; ++r)
#pragma unroll
        for (int c = 0; c < 8; ++c) acc[r][c] += a[r] * w[c];
    }
    __syncthreads();
  }
#pragma unroll
  for (int r = 0; r < 16; ++r) {
    float* Crow = &C[(size_t)rowid[16 * rowq + r] * 128 + 8 * colq];
    *(float4*)&Crow[0] = make_float4(acc[r][0], acc[r][1], acc[r][2], acc[r][3]);
    *(float4*)&Crow[4] = make_float4(acc[r][4], acc[r][5], acc[r][6], acc[r][7]);
  }
}

// ---- feature aggregation + bias + relu + fused score matvec ---------------
__global__ __launch_bounds__(256) void k_agg(const float4* __restrict__ t4,
                                             const int* __restrict__ off,
                                             const int* __restrict__ srcp,
                                             const float* __restrict__ dinv,
                                             const float* __restrict__ selfw,
                                             const float* __restrict__ bias,
                                             const float* __restrict__ Wp,
                                             float4* __restrict__ h4,
                                             float* __restrict__ t1,
                                             const int* __restrict__ kept,
                                             int kshift) {
  int chunk = gridDim.x >> 3;
  int bs = ((blockIdx.x & 7) * chunk) + (blockIdx.x >> 3);  // XCD L2 locality
  int q = bs * 8 + (threadIdx.x >> 5);
  int node;
  if (kept) {
    int g = q >> kshift;
    node = kept[g * N_ + (q - (g << kshift))];
  } else {
    node = q;
  }
  const int lane = threadIdx.x & 31;
  const float dvi = dinv[node];
  float sw = selfw[node];
  float4 self = t4[(size_t)node * 32 + lane];
  float4 acc = make_float4(sw * self.x, sw * self.y, sw * self.z, sw * self.w);
  int s = off[node], en = off[node + 1];
  int j = s;
  for (; j + 4 <= en; j += 4) {
    int s0 = srcp[j], s1 = srcp[j + 1], s2 = srcp[j + 2], s3 = srcp[j + 3];
    float c0 = dinv[s0] * dvi, c1 = dinv[s1] * dvi;
    float c2 = dinv[s2] * dvi, c3 = dinv[s3] * dvi;
    float4 r0 = t4[(size_t)s0 * 32 + lane];
    float4 r1 = t4[(size_t)s1 * 32 + lane];
    float4 r2 = t4[(size_t)s2 * 32 + lane];
    float4 r3 = t4[(size_t)s3 * 32 + lane];
    acc.x += c0 * r0.x + c1 * r1.x + c2 * r2.x + c3 * r3.x;
    acc.y += c0 * r0.y + c1 * r1.y + c2 * r2.y + c3 * r3.y;
    acc.z += c0 * r0.z + c1 * r1.z + c2 * r2.z + c3 * r3.z;
    acc.w += c0 * r0.w + c1 * r1.w + c2 * r2.w + c3 * r3.w;
  }
  for (; j < en; ++j) {
    int s0 = srcp[j];
    float c0 = dinv[s0] * dvi;
    float4 r0 = t4[(size_t)s0 * 32 + lane];
    acc.x += c0 * r0.x; acc.y += c0 * r0.y; acc.z += c0 * r0.z; acc.w += c0 * r0.w;
  }
  float4 b4 = ((const float4*)bias)[lane];
  acc.x = fmaxf(acc.x + b4.x, 0.f);
  acc.y = fmaxf(acc.y + b4.y, 0.f);
  acc.z = fmaxf(acc.z + b4.z, 0.f);
  acc.w = fmaxf(acc.w + b4.w, 0.f);
  h4[(size_t)node * 32 + lane] = acc;
  float4 wp = ((const float4*)Wp)[lane];
  float part = acc.x * wp.x + acc.y * wp.y + acc.z * wp.z + acc.w * wp.w;
#pragma unroll
  for (int o = 16; o > 0; o >>= 1) part += __shfl_down(part, o, 32);
  if (lane == 0) t1[node] = part;
}

// ---- fused pool: score agg + radix top-k + scale + next-layer deg + kept --
__global__ __launch_bounds__(1024) void k_pool(const float* __restrict__ t1,
                                               const int* __restrict__ off,
                                               const int* __restrict__ srcp,
                                               float* __restrict__ dinv,
                                               float* __restrict__ selfw,
                                               const float* __restrict__ bp,
                                               float* __restrict__ scale,
                                               int* __restrict__ kept, int k) {
  __shared__ float st1[2048];
  __shared__ float sdv[2048];
  __shared__ unsigned skey[2048];
  __shared__ float skp[2048];
  __shared__ unsigned hist[256];
  __shared__ unsigned ebits[64];
  __shared__ int wsum[16];
  __shared__ unsigned bc_digit, bc_prev;
  const int g = blockIdx.x, t = threadIdx.x;
  const int base = g * N_;
  st1[t] = t1[base + t];
  st1[t + 1024] = t1[base + t + 1024];
  sdv[t] = dinv[base + t];
  sdv[t + 1024] = dinv[base + t + 1024];
  float sw[2] = {selfw[base + t], selfw[base + t + 1024]};
  if (t < 64) ebits[t] = 0u;
  if (t < 256) hist[t] = 0u;
  __syncthreads();
  float raw[2];
  unsigned key[2];
  float bpv = bp[0];
#pragma unroll
  for (int q = 0; q < 2; ++q) {
    int n = t + q * 1024;
    float di = sdv[n];
    float a = 0.f;
    int s = off[base + n], en = off[base + n + 1];
    for (int j = s; j < en; ++j) {
      int sl = srcp[j] - base;
      a += sdv[sl] * st1[sl];
    }
    raw[q] = sw[q] * st1[n] + di * a + bpv;
    unsigned u = __float_as_uint(raw[q]);
    u = (u & 0x80000000u) ? ~u : (u | 0x80000000u);
    u = ~u;  // descending
    if (di <= 0.f) u = 0xFFFFFFFFu;
    key[q] = u;
    skey[n] = u;
  }
  __syncthreads();
  unsigned prefix = 0u, rem = (unsigned)k;
  for (int shift = 24; shift >= 0; shift -= 8) {
    unsigned mask = (shift == 24) ? 0u : (0xFFFFFFFFu << (shift + 8));
#pragma unroll
    for (int q = 0; q < 2; ++q)
      if ((key[q] & mask) == prefix) atomicAdd(&hist[(key[q] >> shift) & 255u], 1u);
    __syncthreads();
    for (int o = 1; o < 256; o <<= 1) {
      unsigned v = 0u;
      if (t < 256 && t >= o) v = hist[t - o];
      __syncthreads();
      if (t < 256) hist[t] += v;
      __syncthreads();
    }
    if (t < 256) {
      unsigned inc = hist[t], exc = t ? hist[t - 1] : 0u;
      if (inc >= rem && exc < rem) { bc_digit = (unsigned)t; bc_prev = exc; }
    }
    __syncthreads();
    prefix |= bc_digit << shift;
    rem -= bc_prev;
    if (t < 256) hist[t] = 0u;
    __syncthreads();
  }
  const unsigned Tkey = prefix;
  const int need = (int)rem;
#pragma unroll
  for (int q = 0; q < 2; ++q) {
    int n = t + q * 1024;
    if (key[q] == Tkey) atomicOr(&ebits[n >> 5], 1u << (n & 31));
  }
  __syncthreads();
#pragma unroll
  for (int q = 0; q < 2; ++q) {
    int n = t + q * 1024;
    float kp;
    if (key[q] < Tkey) {
      kp = 1.f;
    } else if (key[q] == Tkey) {
      int w = n >> 5;
      int rank = __popc(ebits[w] & ((1u << (n & 31)) - 1u));
      for (int u = 0; u < w; ++u) rank += __popc(ebits[u]);
      kp = (rank < need) ? 1.f : 0.f;
    } else {
      kp = 0.f;
    }
    skp[n] = kp;
    scale[base + n] = kp * tanhf(raw[q]);
  }
  __syncthreads();
  {
    int lane = t & 63, w = t >> 6;
    int a0 = (int)skp[2 * t], a1 = (int)skp[2 * t + 1];
    int ps = a0 + a1;
    int v = ps;
#pragma unroll
    for (int o = 1; o < 64; o <<= 1) {
      int nv = __shfl_up(v, o);
      if (lane >= o) v += nv;
    }
    if (lane == 63) wsum[w] = v;
    __syncthreads();
    if (t == 0) {
      int accv = 0;
      for (int i = 0; i < 16; ++i) { int tmp = wsum[i]; wsum[i] = accv; accv += tmp; }
    }
    __syncthreads();
    int excl = wsum[w] + v - ps;
    if (a0) kept[base + excl] = base + 2 * t;
    if (a1) kept[base + excl + a0] = base + 2 * t + 1;
  }
#pragma unroll
  for (int q = 0; q < 2; ++q) {
    int n = t + q * 1024;
    float nm = skp[n];
    float d = nm;
    int s = off[base + n], en = off[base + n + 1];
    for (int j = s; j < en; ++j) d += skp[srcp[j] - base];
    float di = (nm > 0.f) ? (1.f / sqrtf(d)) : 0.f;
    dinv[base + n] = di;
    selfw[base + n] = di * di * nm;
  }
}

// ---- readout stage 1 over kept list ---------------------------------------
__global__ __launch_bounds__(256) void k_readout1(const float4* __restrict__ h4,
                                                  const float* __restrict__ scale,
                                                  const int* __restrict__ kept,
                                                  int perpart, int npg,
                                                  float4* __restrict__ pmx,
                                                  float4* __restrict__ psm) {
  __shared__ float4 smx[256], ssm[256];
  const int g = blockIdx.x, part = blockIdx.y;
  const int lane = threadIdx.x & 31;
  const int ng = threadIdx.x >> 5;
  float4 mx = make_float4(-INFINITY, -INFINITY, -INFINITY, -INFINITY);
  float4 sm = make_float4(0.f, 0.f, 0.f, 0.f);
  for (int it = 0; it < npg; ++it) {
    int node = kept[g * N_ + part * perpart + it * 8 + ng];
    float sc = scale[node];
    float4 v = h4[(size_t)node * 32 + lane];
    v.x *= sc; v.y *= sc; v.z *= sc; v.w *= sc;
    mx.x = fmaxf(mx.x, v.x); mx.y = fmaxf(mx.y, v.y);
    mx.z = fmaxf(mx.z, v.z); mx.w = fmaxf(mx.w, v.w);
    sm.x += v.x; sm.y += v.y; sm.z += v.z; sm.w += v.w;
  }
  smx[threadIdx.x] = mx;
  ssm[threadIdx.x] = sm;
  __syncthreads();
#pragma unroll
  for (int d = 4; d >= 1; d >>= 1) {
    if (ng < d) {
      float4 omx = smx[threadIdx.x + d * 32];
      float4 osm = ssm[threadIdx.x + d * 32];
      mx.x = fmaxf(mx.x, omx.x); mx.y = fmaxf(mx.y, omx.y);
      mx.z = fmaxf(mx.z, omx.z); mx.w = fmaxf(mx.w, omx.w);
      sm.x += osm.x; sm.y += osm.y; sm.z += osm.z; sm.w += osm.w;
      smx[threadIdx.x] = mx;
      ssm[threadIdx.x] = sm;
    }
    __syncthreads();
  }
  if (ng == 0) {
    pmx[(size_t)(g * RPARTS + part) * 32 + lane] = mx;
    psm[(size_t)(g * RPARTS + part) * 32 + lane] = sm;
  }
}

// ---- MLP head + log_softmax (readout stage 2 folded in) --------------------
__global__ __launch_bounds__(128) void k_mlp(const float* __restrict__ pmx0,
                                             const float* __restrict__ psm0,
                                             const float* __restrict__ pmx1,
                                             const float* __restrict__ psm1,
                                             const float* __restrict__ pmx2,
                                             const float* __restrict__ psm2,
                                             const float* __restrict__ W1,
                                             const float* __restrict__ b1,
                                             const float* __restrict__ W2,
                                             const float* __restrict__ b2,
                                             const float* __restrict__ W3,
                                             const float* __restrict__ b3,
                                             float* __restrict__ out) {
  __shared__ float gr[256], o1[128], o2[64], o3[NCLS];
  int g = blockIdx.x, t = threadIdx.x;
  const float* PM[3] = {pmx0, pmx1, pmx2};
  const float* PS[3] = {psm0, psm1, psm2};
  const float invK[3] = {1.f / 1024.f, 1.f / 512.f, 1.f / 256.f};
  float a_mx = 0.f, a_sm = 0.f;
#pragma unroll
  for (int l = 0; l < 3; ++l) {
    float mx = -INFINITY, sm = 0.f;
    for (int p = 0; p < RPARTS; ++p) {
      mx = fmaxf(mx, PM[l][(size_t)(g * RPARTS + p) * 128 + t]);
      sm += PS[l][(size_t)(g * RPARTS + p) * 128 + t];
    }
    a_mx += mx;
    a_sm += sm * invK[l];
  }
  gr[t] = a_mx;
  gr[t + 128] = a_sm;
  __syncthreads();
  float a = b1[t];
  for (int kk = 0; kk < 256; ++kk) a += gr[kk] * W1[kk * 128 + t];
  o1[t] = fmaxf(a, 0.f);
  __syncthreads();
  if (t < 64) {
    float a2 = b2[t];
    for (int kk = 0; kk < 128; ++kk) a2 += o1[kk] * W2[kk * 64 + t];
    o2[t] = fmaxf(a2, 0.f);
  }
  __syncthreads();
  if (t < NCLS) {
    float a3 = b3[t];
    for (int kk = 0; kk < 64; ++kk) a3 += o2[kk] * W3[kk * NCLS + t];
    o3[t] = a3;
  }
  __syncthreads();
  if (t == 0) {
    float m = -INFINITY;
    for (int c = 0; c < NCLS; ++c) m = fmaxf(m, o3[c]);
    float sum = 0.f;
    for (int c = 0; c < NCLS; ++c) sum += expf(o3[c] - m);
    float lse = logf(sum);
    for (int c = 0; c < NCLS; ++c) out[g * NCLS + c] = o3[c] - m - lse;
  }
}

}  // namespace

extern "C" void kernel_launch(void* const* d_in, const int* in_sizes, int n_in,
                              void* d_out, int out_size, void* d_ws, size_t ws_size,
                              hipStream_t stream) {
  const float* x = (const float*)d_in[0];
  const int* ei = (const int*)d_in[1];
  const int* src = ei;
  const int* dst = ei + E_;
  const float* Wl[3]  = {(const float*)d_in[3], (const float*)d_in[7], (const float*)d_in[11]};
  const float* bl[3]  = {(const float*)d_in[4], (const float*)d_in[8], (const float*)d_in[12]};
  const float* Wpl[3] = {(const float*)d_in[5], (const float*)d_in[9], (const float*)d_in[13]};
  const float* bpl[3] = {(const float*)d_in[6], (const float*)d_in[10], (const float*)d_in[14]};
  const float* l1W = (const float*)d_in[15];
  const float* l1b = (const float*)d_in[16];
  const float* l2W = (const float*)d_in[17];
  const float* l2b = (const float*)d_in[18];
  const float* l3W = (const float*)d_in[19];
  const float* l3b = (const float*)d_in[20];

  char* p = (char*)d_ws;
  auto alloc = [&](size_t bytes) -> void* {
    void* r = (void*)p;
    p += (bytes + 255) & ~size_t(255);
    return r;
  };
  float* h      = (float*)alloc((size_t)NT * 128 * 4);
  float* t      = (float*)alloc((size_t)NT * 128 * 4);
  float* dinv   = (float*)alloc(NT * 4);
  float* selfw  = (float*)alloc(NT * 4);
  float* t1     = (float*)alloc(NT * 4);
  float* scale  = (float*)alloc(NT * 4);
  int*   srcp   = (int*)alloc(E_ * 4);
  int*   off    = (int*)alloc((NT + 1) * 4);
  int*   cnt    = (int*)alloc(NT * 4);
  int*   cursor = (int*)alloc(NT * 4);
  int*   bsum   = (int*)alloc(256 * 4);
  int*   kept0  = (int*)alloc(NT * 4);
  int*   kept1  = (int*)alloc(NT * 4);
  int*   kept2  = (int*)alloc(NT * 4);
  float* pmx[3], * psm[3];
  for (int l = 0; l < 3; ++l) {
    pmx[l] = (float*)alloc((size_t)B_ * RPARTS * 128 * 4);
    psm[l] = (float*)alloc((size_t)B_ * RPARTS * 128 * 4);
  }

  int* keptL[3] = {kept0, kept1, kept2};
  const int K[3] = {1024, 512, 256};
  const int KSH[3] = {10, 9, 8};

  hipMemsetAsync(cnt, 0, NT * 4, stream);

  k_count<<<E_ / 256, 256, 0, stream>>>(dst, cnt);
  k_scan1<<<256, 256, 0, stream>>>(cnt, off, bsum);
  k_scan3<<<256, 256, 0, stream>>>(off, bsum, cnt, cursor, dinv, selfw, scale);
  k_fill_srcp<<<E_ / 256, 256, 0, stream>>>(src, dst, cursor, srcp);

  const float* inF = x;
  for (int l = 0; l < 3; ++l) {
    const int* inKept = (l == 0) ? nullptr : keptL[l - 1];
    int inKsh = (l == 0) ? 11 : KSH[l - 1];
    int nrows = (l == 0) ? NT : B_ * K[l - 1];
    k_matmul<<<nrows / 256, 256, 0, stream>>>(inF, scale, Wl[l], t, inKept, inKsh);
    k_agg<<<nrows / 8, 256, 0, stream>>>((const float4*)t, off, srcp, dinv, selfw,
                                         bl[l], Wpl[l], (float4*)h, t1, inKept, inKsh);
    k_pool<<<B_, 1024, 0, stream>>>(t1, off, srcp, dinv, selfw, bpl[l], scale,
                                    keptL[l], K[l]);
    k_readout1<<<dim3(B_, RPARTS), 256, 0, stream>>>((const float4*)h, scale, keptL[l],
                                                     K[l] / RPARTS, K[l] / RPARTS / 8,
                                                     (float4*)pmx[l], (float4*)psm[l]);
    inF = h;
  }
  k_mlp<<<B_, 128, 0, stream>>>(pmx[0], psm[0], pmx[1], psm[1], pmx[2], psm[2],
                                l1W, l1b, l2W, l2b, l3W, l3b, (float*)d_out);
}

// Round 6
// 399.570 us; speedup vs baseline: 1.0698x; 1.0698x over previous
//
#include <hip/hip_runtime.h>
#include <math.h>

// ---------------------------------------------------------------------------
// SAGPool GNN forward: 3x [GCNConv -> SAGPool(top-k) -> readout] + MLP head.
// B=32 graphs x N=2048 nodes; E=524288; 128 feats; K = 1024/512/256.
// R6 changes vs R5 (427us; 16x8 matmul REGRESSED: VGPR spill @108, occ 9%):
//   - matmul: 8x8 register tile (64 acc VGPRs, no spill), 128-row x 128-col
//     block, grid 512/256/128 (>=2 blocks/CU where it matters), 34KB LDS
//     (4 blocks/CU). Conflict-free transposed-A staging (stride-1 stores).
//   - k_agg: predicated gather (skip coef==0 rows -> saves ~40% of L1/L2
//     gather traffic; numerically identical).
//   - keeps R5's dispatch fusions (scan3 fold, mlp-readout2 fold).
// ---------------------------------------------------------------------------

namespace {

constexpr int B_  = 32;
constexpr int N_  = 2048;
constexpr int NT  = B_ * N_;        // 65536
constexpr int E_  = B_ * 16384;     // 524288
constexpr int NCLS = 10;
constexpr int RPARTS = 32;
constexpr int AST = 132;            // LDS row stride (128 + 4 pad)

// ---- CSR build -------------------------------------------------------------
__global__ void k_count(const int* __restrict__ dst, int* __restrict__ cnt) {
  int e = blockIdx.x * 256 + threadIdx.x;
  if (e < E_) atomicAdd(&cnt[dst[e]], 1);
}

__global__ void k_scan1(const int* __restrict__ cnt, int* __restrict__ off,
                        int* __restrict__ bsum) {
  __shared__ int s[256];
  int t = threadIdx.x;
  int i = blockIdx.x * 256 + t;
  int v = cnt[i];
  s[t] = v;
  __syncthreads();
  for (int d = 1; d < 256; d <<= 1) {
    int add = (t >= d) ? s[t - d] : 0;
    __syncthreads();
    s[t] += add;
    __syncthreads();
  }
  off[i] = s[t] - v;  // exclusive within block
  if (t == 255) bsum[blockIdx.x] = s[255];
}

// scan3: adds bsum prefix (block rescans bsum itself), writes cursor,
// and computes layer-0 deg/dinv/selfw + scale=1.
__global__ void k_scan3(int* __restrict__ off, const int* __restrict__ bsum,
                        const int* __restrict__ cnt, int* __restrict__ cursor,
                        float* __restrict__ dinv, float* __restrict__ selfw,
                        float* __restrict__ scale) {
  __shared__ int sb[256];
  int t = threadIdx.x;
  sb[t] = bsum[t];
  __syncthreads();
  for (int d = 1; d < 256; d <<= 1) {
    int add = (t >= d) ? sb[t - d] : 0;
    __syncthreads();
    sb[t] += add;
    __syncthreads();
  }
  int prefix = (blockIdx.x == 0) ? 0 : sb[blockIdx.x - 1];
  int i = blockIdx.x * 256 + t;
  int v = off[i] + prefix;
  off[i] = v;
  cursor[i] = v;
  if (i == NT - 1) off[NT] = E_;
  float d = 1.f + (float)cnt[i];
  float di = 1.f / sqrtf(d);
  dinv[i] = di;
  selfw[i] = di * di;
  scale[i] = 1.f;
}

__global__ void k_fill_srcp(const int* __restrict__ src, const int* __restrict__ dst,
                            int* __restrict__ cursor, int* __restrict__ srcp) {
  int e = blockIdx.x * 256 + threadIdx.x;
  if (e < E_) {
    int p = atomicAdd(&cursor[dst[e]], 1);
    srcp[p] = src[e];
  }
}

// ---- dense matmul: C[rows x 128] = (scale .* A)[rows x 128] @ W ------------
// 128-row x 128-col tile per 256-thread block; 8 rows x 8 cols per thread.
// A staged transposed [kk][row] (stride 132, stride-1 lane stores = no
// conflicts); W staged [kk][col]. acc = 64 VGPRs -> no spill, 4 waves/SIMD.
__global__ __launch_bounds__(256) void k_matmul(const float* __restrict__ A,
                                                const float* __restrict__ scale,
                                                const float* __restrict__ W,
                                                float* __restrict__ C,
                                                const int* __restrict__ kept,
                                                int kshift) {
  __shared__ float Ast[32 * AST];
  __shared__ float Ws[32 * AST];
  __shared__ int rowid[128];
  __shared__ float rsc[128];
  const int tid = threadIdx.x;
  if (tid < 128) {
    int q = blockIdx.x * 128 + tid;
    int row;
    if (kept) {
      int g = q >> kshift;
      row = kept[g * N_ + (q - (g << kshift))];
    } else {
      row = q;
    }
    rowid[tid] = row;
    rsc[tid] = scale[row];
  }
  __syncthreads();
  const int rowq = tid >> 4;   // 0..15 -> rows 8*rowq..+7
  const int colq = tid & 15;   // 0..15 -> cols 8*colq..+7
  float acc[8][8] = {};
  for (int k0 = 0; k0 < 128; k0 += 32) {
    // stage A (128 rows x 32 k), transposed; scale folded in.
    // lane->row is stride-1 => LDS stores hit 32 banks 2-wide (free).
#pragma unroll
    for (int i = 0; i < 4; ++i) {
      int idx = tid + 256 * i;
      int row = idx & 127, fq = idx >> 7;  // fq 0..7
      float4 v = *(const float4*)&A[(size_t)rowid[row] * 128 + k0 + 4 * fq];
      float sc = rsc[row];
      Ast[(4 * fq + 0) * AST + row] = v.x * sc;
      Ast[(4 * fq + 1) * AST + row] = v.y * sc;
      Ast[(4 * fq + 2) * AST + row] = v.z * sc;
      Ast[(4 * fq + 3) * AST + row] = v.w * sc;
    }
    // stage W (32 k x 128 cols)
#pragma unroll
    for (int i = 0; i < 4; ++i) {
      int idx = tid + 256 * i;
      int kk = idx >> 5, cf = idx & 31;
      *(float4*)&Ws[kk * AST + 4 * cf] =
          *(const float4*)&W[(size_t)(k0 + kk) * 128 + 4 * cf];
    }
    __syncthreads();
#pragma unroll 2
    for (int kk = 0; kk < 32; ++kk) {
      float4 a0 = *(const float4*)&Ast[kk * AST + 8 * rowq];
      float4 a1 = *(const float4*)&Ast[kk * AST + 8 * rowq + 4];
      float4 w0 = *(const float4*)&Ws[kk * AST + 8 * colq];
      float4 w1 = *(const float4*)&Ws[kk * AST + 8 * colq + 4];
      float a[8] = {a0.x, a0.y, a0.z, a0.w, a1.x, a1.y, a1.z, a1.w};
      float w[8] = {w0.x, w0.y, w0.z, w0.w, w1.x, w1.y, w1.z, w1.w};
#pragma unroll
      for (int r = 0; r < 8; ++r)
#pragma unroll
        for (int c = 0; c < 8; ++c) acc[r][c] += a[r] * w[c];
    }
    __syncthreads();
  }
#pragma unroll
  for (int r = 0; r < 8; ++r) {
    float* Crow = &C[(size_t)rowid[8 * rowq + r] * 128 + 8 * colq];
    *(float4*)&Crow[0] = make_float4(acc[r][0], acc[r][1], acc[r][2], acc[r][3]);
    *(float4*)&Crow[4] = make_float4(acc[r][4], acc[r][5], acc[r][6], acc[r][7]);
  }
}

// ---- feature aggregation + bias + relu + fused score matvec ---------------
__global__ __launch_bounds__(256) void k_agg(const float4* __restrict__ t4,
                                             const int* __restrict__ off,
                                             const int* __restrict__ srcp,
                                             const float* __restrict__ dinv,
                                             const float* __restrict__ selfw,
                                             const float* __restrict__ bias,
                                             const float* __restrict__ Wp,
                                             float4* __restrict__ h4,
                                             float* __restrict__ t1,
                                             const int* __restrict__ kept,
                                             int kshift) {
  int chunk = gridDim.x >> 3;
  int bs = ((blockIdx.x & 7) * chunk) + (blockIdx.x >> 3);  // XCD L2 locality
  int q = bs * 8 + (threadIdx.x >> 5);
  int node;
  if (kept) {
    int g = q >> kshift;
    node = kept[g * N_ + (q - (g << kshift))];
  } else {
    node = q;
  }
  const int lane = threadIdx.x & 31;
  const float dvi = dinv[node];
  float sw = selfw[node];
  float4 self = t4[(size_t)node * 32 + lane];
  float4 acc = make_float4(sw * self.x, sw * self.y, sw * self.z, sw * self.w);
  int s = off[node], en = off[node + 1];
  int j = s;
  for (; j + 4 <= en; j += 4) {
    int s0 = srcp[j], s1 = srcp[j + 1], s2 = srcp[j + 2], s3 = srcp[j + 3];
    float c0 = dinv[s0] * dvi, c1 = dinv[s1] * dvi;
    float c2 = dinv[s2] * dvi, c3 = dinv[s3] * dvi;
    if (c0 != 0.f) {
      float4 r0 = t4[(size_t)s0 * 32 + lane];
      acc.x += c0 * r0.x; acc.y += c0 * r0.y; acc.z += c0 * r0.z; acc.w += c0 * r0.w;
    }
    if (c1 != 0.f) {
      float4 r1 = t4[(size_t)s1 * 32 + lane];
      acc.x += c1 * r1.x; acc.y += c1 * r1.y; acc.z += c1 * r1.z; acc.w += c1 * r1.w;
    }
    if (c2 != 0.f) {
      float4 r2 = t4[(size_t)s2 * 32 + lane];
      acc.x += c2 * r2.x; acc.y += c2 * r2.y; acc.z += c2 * r2.z; acc.w += c2 * r2.w;
    }
    if (c3 != 0.f) {
      float4 r3 = t4[(size_t)s3 * 32 + lane];
      acc.x += c3 * r3.x; acc.y += c3 * r3.y; acc.z += c3 * r3.z; acc.w += c3 * r3.w;
    }
  }
  for (; j < en; ++j) {
    int s0 = srcp[j];
    float c0 = dinv[s0] * dvi;
    if (c0 != 0.f) {
      float4 r0 = t4[(size_t)s0 * 32 + lane];
      acc.x += c0 * r0.x; acc.y += c0 * r0.y; acc.z += c0 * r0.z; acc.w += c0 * r0.w;
    }
  }
  float4 b4 = ((const float4*)bias)[lane];
  acc.x = fmaxf(acc.x + b4.x, 0.f);
  acc.y = fmaxf(acc.y + b4.y, 0.f);
  acc.z = fmaxf(acc.z + b4.z, 0.f);
  acc.w = fmaxf(acc.w + b4.w, 0.f);
  h4[(size_t)node * 32 + lane] = acc;
  float4 wp = ((const float4*)Wp)[lane];
  float part = acc.x * wp.x + acc.y * wp.y + acc.z * wp.z + acc.w * wp.w;
#pragma unroll
  for (int o = 16; o > 0; o >>= 1) part += __shfl_down(part, o, 32);
  if (lane == 0) t1[node] = part;
}

// ---- fused pool: score agg + radix top-k + scale + next-layer deg + kept --
__global__ __launch_bounds__(1024) void k_pool(const float* __restrict__ t1,
                                               const int* __restrict__ off,
                                               const int* __restrict__ srcp,
                                               float* __restrict__ dinv,
                                               float* __restrict__ selfw,
                                               const float* __restrict__ bp,
                                               float* __restrict__ scale,
                                               int* __restrict__ kept, int k) {
  __shared__ float st1[2048];
  __shared__ float sdv[2048];
  __shared__ float skp[2048];
  __shared__ unsigned hist[256];
  __shared__ unsigned ebits[64];
  __shared__ int wsum[16];
  __shared__ unsigned bc_digit, bc_prev;
  const int g = blockIdx.x, t = threadIdx.x;
  const int base = g * N_;
  st1[t] = t1[base + t];
  st1[t + 1024] = t1[base + t + 1024];
  sdv[t] = dinv[base + t];
  sdv[t + 1024] = dinv[base + t + 1024];
  float sw[2] = {selfw[base + t], selfw[base + t + 1024]};
  if (t < 64) ebits[t] = 0u;
  if (t < 256) hist[t] = 0u;
  __syncthreads();
  float raw[2];
  unsigned key[2];
  float bpv = bp[0];
#pragma unroll
  for (int q = 0; q < 2; ++q) {
    int n = t + q * 1024;
    float di = sdv[n];
    float a = 0.f;
    int s = off[base + n], en = off[base + n + 1];
    for (int j = s; j < en; ++j) {
      int sl = srcp[j] - base;
      a += sdv[sl] * st1[sl];
    }
    raw[q] = sw[q] * st1[n] + di * a + bpv;
    unsigned u = __float_as_uint(raw[q]);
    u = (u & 0x80000000u) ? ~u : (u | 0x80000000u);
    u = ~u;  // descending
    if (di <= 0.f) u = 0xFFFFFFFFu;
    key[q] = u;
  }
  __syncthreads();
  unsigned prefix = 0u, rem = (unsigned)k;
  for (int shift = 24; shift >= 0; shift -= 8) {
    unsigned mask = (shift == 24) ? 0u : (0xFFFFFFFFu << (shift + 8));
#pragma unroll
    for (int q = 0; q < 2; ++q)
      if ((key[q] & mask) == prefix) atomicAdd(&hist[(key[q] >> shift) & 255u], 1u);
    __syncthreads();
    for (int o = 1; o < 256; o <<= 1) {
      unsigned v = 0u;
      if (t < 256 && t >= o) v = hist[t - o];
      __syncthreads();
      if (t < 256) hist[t] += v;
      __syncthreads();
    }
    if (t < 256) {
      unsigned inc = hist[t], exc = t ? hist[t - 1] : 0u;
      if (inc >= rem && exc < rem) { bc_digit = (unsigned)t; bc_prev = exc; }
    }
    __syncthreads();
    prefix |= bc_digit << shift;
    rem -= bc_prev;
    if (t < 256) hist[t] = 0u;
    __syncthreads();
  }
  const unsigned Tkey = prefix;
  const int need = (int)rem;
#pragma unroll
  for (int q = 0; q < 2; ++q) {
    int n = t + q * 1024;
    if (key[q] == Tkey) atomicOr(&ebits[n >> 5], 1u << (n & 31));
  }
  __syncthreads();
#pragma unroll
  for (int q = 0; q < 2; ++q) {
    int n = t + q * 1024;
    float kp;
    if (key[q] < Tkey) {
      kp = 1.f;
    } else if (key[q] == Tkey) {
      int w = n >> 5;
      int rank = __popc(ebits[w] & ((1u << (n & 31)) - 1u));
      for (int u = 0; u < w; ++u) rank += __popc(ebits[u]);
      kp = (rank < need) ? 1.f : 0.f;
    } else {
      kp = 0.f;
    }
    skp[n] = kp;
    scale[base + n] = kp * tanhf(raw[q]);
  }
  __syncthreads();
  {
    int lane = t & 63, w = t >> 6;
    int a0 = (int)skp[2 * t], a1 = (int)skp[2 * t + 1];
    int ps = a0 + a1;
    int v = ps;
#pragma unroll
    for (int o = 1; o < 64; o <<= 1) {
      int nv = __shfl_up(v, o);
      if (lane >= o) v += nv;
    }
    if (lane == 63) wsum[w] = v;
    __syncthreads();
    if (t == 0) {
      int accv = 0;
      for (int i = 0; i < 16; ++i) { int tmp = wsum[i]; wsum[i] = accv; accv += tmp; }
    }
    __syncthreads();
    int excl = wsum[w] + v - ps;
    if (a0) kept[base + excl] = base + 2 * t;
    if (a1) kept[base + excl + a0] = base + 2 * t + 1;
  }
#pragma unroll
  for (int q = 0; q < 2; ++q) {
    int n = t + q * 1024;
    float nm = skp[n];
    float d = nm;
    int s = off[base + n], en = off[base + n + 1];
    for (int j = s; j < en; ++j) d += skp[srcp[j] - base];
    float di = (nm > 0.f) ? (1.f / sqrtf(d)) : 0.f;
    dinv[base + n] = di;
    selfw[base + n] = di * di * nm;
  }
}

// ---- readout stage 1 over kept list ---------------------------------------
__global__ __launch_bounds__(256) void k_readout1(const float4* __restrict__ h4,
                                                  const float* __restrict__ scale,
                                                  const int* __restrict__ kept,
                                                  int perpart, int npg,
                                                  float4* __restrict__ pmx,
                                                  float4* __restrict__ psm) {
  __shared__ float4 smx[256], ssm[256];
  const int g = blockIdx.x, part = blockIdx.y;
  const int lane = threadIdx.x & 31;
  const int ng = threadIdx.x >> 5;
  float4 mx = make_float4(-INFINITY, -INFINITY, -INFINITY, -INFINITY);
  float4 sm = make_float4(0.f, 0.f, 0.f, 0.f);
  for (int it = 0; it < npg; ++it) {
    int node = kept[g * N_ + part * perpart + it * 8 + ng];
    float sc = scale[node];
    float4 v = h4[(size_t)node * 32 + lane];
    v.x *= sc; v.y *= sc; v.z *= sc; v.w *= sc;
    mx.x = fmaxf(mx.x, v.x); mx.y = fmaxf(mx.y, v.y);
    mx.z = fmaxf(mx.z, v.z); mx.w = fmaxf(mx.w, v.w);
    sm.x += v.x; sm.y += v.y; sm.z += v.z; sm.w += v.w;
  }
  smx[threadIdx.x] = mx;
  ssm[threadIdx.x] = sm;
  __syncthreads();
#pragma unroll
  for (int d = 4; d >= 1; d >>= 1) {
    if (ng < d) {
      float4 omx = smx[threadIdx.x + d * 32];
      float4 osm = ssm[threadIdx.x + d * 32];
      mx.x = fmaxf(mx.x, omx.x); mx.y = fmaxf(mx.y, omx.y);
      mx.z = fmaxf(mx.z, omx.z); mx.w = fmaxf(mx.w, omx.w);
      sm.x += osm.x; sm.y += osm.y; sm.z += osm.z; sm.w += osm.w;
      smx[threadIdx.x] = mx;
      ssm[threadIdx.x] = sm;
    }
    __syncthreads();
  }
  if (ng == 0) {
    pmx[(size_t)(g * RPARTS + part) * 32 + lane] = mx;
    psm[(size_t)(g * RPARTS + part) * 32 + lane] = sm;
  }
}

// ---- MLP head + log_softmax (readout stage 2 folded in) --------------------
__global__ __launch_bounds__(128) void k_mlp(const float* __restrict__ pmx0,
                                             const float* __restrict__ psm0,
                                             const float* __restrict__ pmx1,
                                             const float* __restrict__ psm1,
                                             const float* __restrict__ pmx2,
                                             const float* __restrict__ psm2,
                                             const float* __restrict__ W1,
                                             const float* __restrict__ b1,
                                             const float* __restrict__ W2,
                                             const float* __restrict__ b2,
                                             const float* __restrict__ W3,
                                             const float* __restrict__ b3,
                                             float* __restrict__ out) {
  __shared__ float gr[256], o1[128], o2[64], o3[NCLS];
  int g = blockIdx.x, t = threadIdx.x;
  const float* PM[3] = {pmx0, pmx1, pmx2};
  const float* PS[3] = {psm0, psm1, psm2};
  const float invK[3] = {1.f / 1024.f, 1.f / 512.f, 1.f / 256.f};
  float a_mx = 0.f, a_sm = 0.f;
#pragma unroll
  for (int l = 0; l < 3; ++l) {
    float mx = -INFINITY, sm = 0.f;
    for (int p = 0; p < RPARTS; ++p) {
      mx = fmaxf(mx, PM[l][(size_t)(g * RPARTS + p) * 128 + t]);
      sm += PS[l][(size_t)(g * RPARTS + p) * 128 + t];
    }
    a_mx += mx;
    a_sm += sm * invK[l];
  }
  gr[t] = a_mx;
  gr[t + 128] = a_sm;
  __syncthreads();
  float a = b1[t];
  for (int kk = 0; kk < 256; ++kk) a += gr[kk] * W1[kk * 128 + t];
  o1[t] = fmaxf(a, 0.f);
  __syncthreads();
  if (t < 64) {
    float a2 = b2[t];
    for (int kk = 0; kk < 128; ++kk) a2 += o1[kk] * W2[kk * 64 + t];
    o2[t] = fmaxf(a2, 0.f);
  }
  __syncthreads();
  if (t < NCLS) {
    float a3 = b3[t];
    for (int kk = 0; kk < 64; ++kk) a3 += o2[kk] * W3[kk * NCLS + t];
    o3[t] = a3;
  }
  __syncthreads();
  if (t == 0) {
    float m = -INFINITY;
    for (int c = 0; c < NCLS; ++c) m = fmaxf(m, o3[c]);
    float sum = 0.f;
    for (int c = 0; c < NCLS; ++c) sum += expf(o3[c] - m);
    float lse = logf(sum);
    for (int c = 0; c < NCLS; ++c) out[g * NCLS + c] = o3[c] - m - lse;
  }
}

}  // namespace

extern "C" void kernel_launch(void* const* d_in, const int* in_sizes, int n_in,
                              void* d_out, int out_size, void* d_ws, size_t ws_size,
                              hipStream_t stream) {
  const float* x = (const float*)d_in[0];
  const int* ei = (const int*)d_in[1];
  const int* src = ei;
  const int* dst = ei + E_;
  const float* Wl[3]  = {(const float*)d_in[3], (const float*)d_in[7], (const float*)d_in[11]};
  const float* bl[3]  = {(const float*)d_in[4], (const float*)d_in[8], (const float*)d_in[12]};
  const float* Wpl[3] = {(const float*)d_in[5], (const float*)d_in[9], (const float*)d_in[13]};
  const float* bpl[3] = {(const float*)d_in[6], (const float*)d_in[10], (const float*)d_in[14]};
  const float* l1W = (const float*)d_in[15];
  const float* l1b = (const float*)d_in[16];
  const float* l2W = (const float*)d_in[17];
  const float* l2b = (const float*)d_in[18];
  const float* l3W = (const float*)d_in[19];
  const float* l3b = (const float*)d_in[20];

  char* p = (char*)d_ws;
  auto alloc = [&](size_t bytes) -> void* {
    void* r = (void*)p;
    p += (bytes + 255) & ~size_t(255);
    return r;
  };
  float* h      = (float*)alloc((size_t)NT * 128 * 4);
  float* t      = (float*)alloc((size_t)NT * 128 * 4);
  float* dinv   = (float*)alloc(NT * 4);
  float* selfw  = (float*)alloc(NT * 4);
  float* t1     = (float*)alloc(NT * 4);
  float* scale  = (float*)alloc(NT * 4);
  int*   srcp   = (int*)alloc(E_ * 4);
  int*   off    = (int*)alloc((NT + 1) * 4);
  int*   cnt    = (int*)alloc(NT * 4);
  int*   cursor = (int*)alloc(NT * 4);
  int*   bsum   = (int*)alloc(256 * 4);
  int*   kept0  = (int*)alloc(NT * 4);
  int*   kept1  = (int*)alloc(NT * 4);
  int*   kept2  = (int*)alloc(NT * 4);
  float* pmx[3], * psm[3];
  for (int l = 0; l < 3; ++l) {
    pmx[l] = (float*)alloc((size_t)B_ * RPARTS * 128 * 4);
    psm[l] = (float*)alloc((size_t)B_ * RPARTS * 128 * 4);
  }

  int* keptL[3] = {kept0, kept1, kept2};
  const int K[3] = {1024, 512, 256};
  const int KSH[3] = {10, 9, 8};

  hipMemsetAsync(cnt, 0, NT * 4, stream);

  k_count<<<E_ / 256, 256, 0, stream>>>(dst, cnt);
  k_scan1<<<256, 256, 0, stream>>>(cnt, off, bsum);
  k_scan3<<<256, 256, 0, stream>>>(off, bsum, cnt, cursor, dinv, selfw, scale);
  k_fill_srcp<<<E_ / 256, 256, 0, stream>>>(src, dst, cursor, srcp);

  const float* inF = x;
  for (int l = 0; l < 3; ++l) {
    const int* inKept = (l == 0) ? nullptr : keptL[l - 1];
    int inKsh = (l == 0) ? 11 : KSH[l - 1];
    int nrows = (l == 0) ? NT : B_ * K[l - 1];
    k_matmul<<<nrows / 128, 256, 0, stream>>>(inF, scale, Wl[l], t, inKept, inKsh);
    k_agg<<<nrows / 8, 256, 0, stream>>>((const float4*)t, off, srcp, dinv, selfw,
                                         bl[l], Wpl[l], (float4*)h, t1, inKept, inKsh);
    k_pool<<<B_, 1024, 0, stream>>>(t1, off, srcp, dinv, selfw, bpl[l], scale,
                                    keptL[l], K[l]);
    k_readout1<<<dim3(B_, RPARTS), 256, 0, stream>>>((const float4*)h, scale, keptL[l],
                                                     K[l] / RPARTS, K[l] / RPARTS / 8,
                                                     (float4*)pmx[l], (float4*)psm[l]);
    inF = h;
  }
  k_mlp<<<B_, 128, 0, stream>>>(pmx[0], psm[0], pmx[1], psm[1], pmx[2], psm[2],
                                l1W, l1b, l2W, l2b, l3W, l3b, (float*)d_out);
}